// Round 3
// baseline (1292.661 us; speedup 1.0000x reference)
//
#include <hip/hip_runtime.h>
#include <hip/hip_bf16.h>
#include <math.h>

// Problem constants: T=2048, B=4096, IN_S=1, H=20, OUT_S=1
#define TT 2048
#define BB 4096
#define HH 20

typedef float v2f __attribute__((ext_vector_type(2)));

__device__ __forceinline__ float rcp_fast(float x) {
    return __builtin_amdgcn_rcpf(x);  // v_rcp_f32, ~1 ulp
}
__device__ __forceinline__ float sigm_fast(float x) {
    return rcp_fast(1.0f + __expf(-x));
}
__device__ __forceinline__ float tanh_fast(float x) {
    // tanh(|x|) = (1-e)/(1+e), e = exp(-2|x|) in (0,1] -> no overflow; restore sign.
    float e = __expf(-2.0f * fabsf(x));
    float t = (1.0f - e) * rcp_fast(1.0f + e);
    return copysignf(t, x);
}

// Packed dual fp32 FMA/ADD (CDNA: V_PK_FMA_F32 / V_PK_ADD_F32, VGPR-pair operands).
__device__ __forceinline__ v2f pk_fma(v2f a, v2f b, v2f c) {
    v2f d;
    asm("v_pk_fma_f32 %0, %1, %2, %3" : "=v"(d) : "v"(a), "v"(b), "v"(c));
    return d;
}
__device__ __forceinline__ v2f pk_add(v2f a, v2f b) {
    v2f d;
    asm("v_pk_add_f32 %0, %1, %2" : "=v"(d) : "v"(a), "v"(b));
    return d;
}

// One wave per block. Lanes [0..19],[20..39],[40..59] = 3 batches; lane -> (group, j).
// Lanes 60..63 idle (compute garbage in their own LDS region, never store).
__global__ __launch_bounds__(64, 1) void lstm_fused_kernel(
    const float* __restrict__ u,      // [T, B, 1]
    const float* __restrict__ W_ih,   // [4H, 1]
    const float* __restrict__ W_hh,   // [4H, H]
    const float* __restrict__ W_out,  // [1, H]
    float* __restrict__ y)            // [T, B, 1]
{
    // Double-buffered by step parity. hdup holds (h_k, h_k) duplicated pairs
    // (feeds gate pk_fmas directly); hpl holds plain h (feeds the y pk_fmas).
    __shared__ __align__(16) float hdup[2][4][2 * HH];
    __shared__ __align__(16) float hpl[2][4][HH];

    const int lane  = threadIdx.x;
    const int group = lane / HH;          // 0..3 (3 == idle)
    const int j     = lane - group * HH;  // 0..19
    const int b_real = blockIdx.x * 3 + group;
    const bool active = (group < 3) && (b_real < BB);
    const int b = active ? b_real : 0;

    // Zero-init both parity buffers (h_{-1} = 0; also keeps idle group-3 region finite).
    for (int i = lane; i < 2 * 4 * 2 * HH; i += 64) ((float*)hdup)[i] = 0.0f;
    for (int i = lane; i < 2 * 4 * HH; i += 64) ((float*)hpl)[i] = 0.0f;
    asm volatile("s_waitcnt lgkmcnt(0)" ::: "memory");

    // ---- Weights in registers, packed by gate pair ----
    v2f wp01[HH];  // (W_hh[i-gate row j][k], W_hh[f-gate row j][k])
    v2f wp23[HH];  // (g-gate, o-gate)
    #pragma unroll
    for (int k = 0; k < HH; ++k) {
        wp01[k].x = W_hh[(0 * HH + j) * HH + k];
        wp01[k].y = W_hh[(1 * HH + j) * HH + k];
        wp23[k].x = W_hh[(2 * HH + j) * HH + k];
        wp23[k].y = W_hh[(3 * HH + j) * HH + k];
    }
    v2f wih01, wih23;
    wih01.x = W_ih[0 * HH + j]; wih01.y = W_ih[1 * HH + j];
    wih23.x = W_ih[2 * HH + j]; wih23.y = W_ih[3 * HH + j];
    v2f wo[HH / 2];  // (W_out[2m], W_out[2m+1])
    #pragma unroll
    for (int m = 0; m < HH / 2; ++m) { wo[m].x = W_out[2 * m]; wo[m].y = W_out[2 * m + 1]; }

    float c = 0.0f;
    const float* __restrict__ up = u + b;
    float* __restrict__ yp = y + b;

    float u_cur[4];
    #pragma unroll
    for (int k = 0; k < 4; ++k) u_cur[k] = up[(size_t)k * BB];

    const v2f zz = {0.0f, 0.0f};

    for (int t4 = 0; t4 < TT; t4 += 4) {
        const int tn = (t4 + 4 < TT) ? (t4 + 4) : t4;
        float u_nxt[4];
        #pragma unroll
        for (int k = 0; k < 4; ++k) u_nxt[k] = up[(size_t)(tn + k) * BB];

        float y4[4];  // y4[tt] = y_{t4+tt-1} (y is one step delayed: it reads h_{t-1})

        #pragma unroll
        for (int tt = 0; tt < 4; ++tt) {
            const float uv = u_cur[tt];
            const int rp = (tt + 1) & 1;  // parity holding h_{t-1}
            const int wp = tt & 1;        // parity to write h_t

            v2f up2; up2.x = uv; up2.y = uv;
            // Split accumulators (even/odd m) halve the dependent chain.
            v2f a01a = pk_fma(up2, wih01, zz), a01b = zz;
            v2f a23a = pk_fma(up2, wih23, zz), a23b = zz;
            v2f aya = zz, ayb = zz;

            const v2f* __restrict__ hd = (const v2f*)&hdup[rp][group][0];  // (h_k,h_k)
            const v2f* __restrict__ hq = (const v2f*)&hpl[rp][group][0];   // (h_2m,h_2m+1)
            #pragma unroll
            for (int m = 0; m < HH / 2; ++m) {
                v2f p0 = hd[2 * m];      // (h_{2m},   h_{2m})
                v2f p1 = hd[2 * m + 1];  // (h_{2m+1}, h_{2m+1})
                v2f pq = hq[m];          // (h_{2m},   h_{2m+1})
                a01a = pk_fma(wp01[2 * m],     p0, a01a);
                a23a = pk_fma(wp23[2 * m],     p0, a23a);
                a01b = pk_fma(wp01[2 * m + 1], p1, a01b);
                a23b = pk_fma(wp23[2 * m + 1], p1, a23b);
                if (m & 1) ayb = pk_fma(wo[m], pq, ayb);
                else       aya = pk_fma(wo[m], pq, aya);
            }
            v2f a01 = pk_add(a01a, a01b);
            v2f a23 = pk_add(a23a, a23b);
            v2f ay  = pk_add(aya, ayb);
            y4[tt] = ay.x + ay.y;  // y_{t-1}

            const float ig = sigm_fast(a01.x);
            const float fg = sigm_fast(a01.y);
            const float gg = tanh_fast(a23.x);
            const float og = sigm_fast(a23.y);
            c = fmaf(fg, c, ig * gg);
            const float h = og * tanh_fast(c);

            // Broadcast h_t (single-wave block: in-order DS pipe + lgkmcnt drain
            // gives cross-lane visibility without s_barrier / vmcnt drain).
            v2f hh2; hh2.x = h; hh2.y = h;
            *(v2f*)&hdup[wp][group][2 * j] = hh2;   // ds_write_b64
            hpl[wp][group][j] = h;                  // ds_write_b32
            asm volatile("s_waitcnt lgkmcnt(0)" ::: "memory");
        }

        // Batched y stores (indices t4-1 .. t4+2), off the critical path.
        if (active && j == 0) {
            #pragma unroll
            for (int k = 0; k < 4; ++k) {
                const int idx = t4 - 1 + k;
                if (idx >= 0) yp[(size_t)idx * BB] = y4[k];
            }
        }

        #pragma unroll
        for (int k = 0; k < 4; ++k) u_cur[k] = u_nxt[k];
    }

    // Epilogue: y_{T-1} from h_{T-1} (T-1 odd -> parity 1).
    {
        const v2f* __restrict__ hq = (const v2f*)&hpl[1][group][0];
        v2f aya = zz, ayb = zz;
        #pragma unroll
        for (int m = 0; m < HH / 2; ++m) {
            if (m & 1) ayb = pk_fma(wo[m], hq[m], ayb);
            else       aya = pk_fma(wo[m], hq[m], aya);
        }
        v2f ay = pk_add(aya, ayb);
        if (active && j == 0) yp[(size_t)(TT - 1) * BB] = ay.x + ay.y;
    }
}

extern "C" void kernel_launch(void* const* d_in, const int* in_sizes, int n_in,
                              void* d_out, int out_size, void* d_ws, size_t ws_size,
                              hipStream_t stream) {
    const float* u     = (const float*)d_in[0];   // [2048, 4096, 1]
    const float* W_ih  = (const float*)d_in[1];   // [80, 1]
    const float* W_hh  = (const float*)d_in[2];   // [80, 20]
    const float* W_out = (const float*)d_in[3];   // [1, 20]
    float* y = (float*)d_out;                      // [2048, 4096, 1]

    const int blocks = (BB + 2) / 3;  // 3 batches per single-wave block -> 1366
    lstm_fused_kernel<<<dim3(blocks), dim3(64), 0, stream>>>(u, W_ih, W_hh, W_out, y);
}